// Round 4
// baseline (127.569 us; speedup 1.0000x reference)
//
#include <hip/hip_runtime.h>

// Problem constants (match reference)
constexpr int Cc  = 128;
constexpr int Hh  = 512;
constexpr int Ww  = 512;
constexpr int HW  = Hh * Ww;          // 262144
constexpr int CHW = Cc * HW;          // 33554432
constexpr int NCHUNK = 16;            // reduction blocks per channel
constexpr int PSTRIDE = 24;           // floats per channel in params

// ---------------------------------------------------------------------------
// Kernel 1: per-channel partial sum / sumsq over pre_x (x[1], second half).
// grid = (NCHUNK, C), block = 256. Each block reduces 16384 contiguous floats.
// Deterministic tree reduction (no float atomics -> replay-stable).
// ---------------------------------------------------------------------------
__global__ __launch_bounds__(256) void pdin_reduce(const float* __restrict__ x,
                                                   float* __restrict__ partials) {
    const int c = blockIdx.y, chunk = blockIdx.x, tid = threadIdx.x;
    const float4* src = reinterpret_cast<const float4*>(
        x + (size_t)CHW + (size_t)c * HW + (size_t)chunk * 16384);
    float s = 0.f, q = 0.f;
#pragma unroll
    for (int i = 0; i < 16; ++i) {
        float4 v = src[tid + i * 256];
        s += (v.x + v.y) + (v.z + v.w);
        q += (v.x * v.x + v.y * v.y) + (v.z * v.z + v.w * v.w);
    }
#pragma unroll
    for (int off = 32; off; off >>= 1) {
        s += __shfl_down(s, off);
        q += __shfl_down(q, off);
    }
    __shared__ float ls[4], lq[4];
    const int wave = tid >> 6, lane = tid & 63;
    if (lane == 0) { ls[wave] = s; lq[wave] = q; }
    __syncthreads();
    if (tid == 0) {
        float S = (ls[0] + ls[1]) + (ls[2] + ls[3]);
        float Q = (lq[0] + lq[1]) + (lq[2] + lq[3]);
        partials[(c * NCHUNK + chunk) * 2 + 0] = S;
        partials[(c * NCHUNK + chunk) * 2 + 1] = Q;
    }
}

// ---------------------------------------------------------------------------
// Kernel 2: finalize stats + build per-channel params (1 block, 128 threads).
// params[c*24]: [0..8] m grid, [9..17] 1/s grid, [18] w, [19] b,
//               [20] scale_pre = w/std, [21] shift_pre = b - mean*scale_pre
// ---------------------------------------------------------------------------
__global__ void pdin_finalize(const float* __restrict__ partials,
                              const float* __restrict__ mt,
                              const float* __restrict__ st,
                              const float* __restrict__ wgt,
                              const float* __restrict__ bia,
                              const int* __restrict__ ya_p, const int* __restrict__ xa_p,
                              const int* __restrict__ pya_p, const int* __restrict__ pxa_p,
                              float* __restrict__ params) {
    const int c = threadIdx.x;
    if (c >= Cc) return;
    float S = 0.f, Q = 0.f;
    for (int k = 0; k < NCHUNK; ++k) {
        S += partials[(c * NCHUNK + k) * 2 + 0];
        Q += partials[(c * NCHUNK + k) * 2 + 1];
    }
    const float Nf = (float)HW;
    const float mean = S / Nf;
    float var = (Q - S * mean) / (Nf - 1.0f);   // ddof=1
    var = fmaxf(var, 0.0f);
    const float stdv = sqrtf(var);

    const int ya = ya_p[0], xa = xa_p[0];
    const int wr = pya_p[0] + 1, wc = pxa_p[0] + 1;   // written table position
    const float* mtc = mt + c * 144;                   // 12x12 tables
    const float* stc = st + c * 144;

    // center of the 3x3 slice, post table-write, pre zero-substitution
    const bool cw = (ya + 1 == wr) && (xa + 1 == wc);
    const float cm = cw ? mean : mtc[(ya + 1) * 12 + (xa + 1)];
    const float cs = cw ? stdv : stc[(ya + 1) * 12 + (xa + 1)];

    float* P = params + c * PSTRIDE;
    for (int r = 0; r < 3; ++r)
        for (int k = 0; k < 3; ++k) {
            const int R = ya + r, L = xa + k;
            const bool hit = (R == wr) && (L == wc);
            float mv = hit ? mean : mtc[R * 12 + L];
            if (mv == 0.0f) mv = cm;
            float sv = hit ? stdv : stc[R * 12 + L];
            if (sv == 0.0f) sv = cs;
            P[r * 3 + k]     = mv;
            P[9 + r * 3 + k] = 1.0f / sv;
        }
    const float w = wgt[c], b = bia[c];
    P[18] = w;
    P[19] = b;
    const float sc = w / stdv;
    P[20] = sc;
    P[21] = b - mean * sc;
}

// ---------------------------------------------------------------------------
// Kernel 3: streaming elementwise pass over both halves.
// grid = (32 rowblocks, C, 2 halves), block = 256, 8 float4 per thread.
// Real half: per-pixel bilinear from the 3x3 grid. A float4 quad always sits
// entirely on one side of the x=256 breakpoint (multiple of 4), so iy/ix are
// quad-uniform; selection is branch-free ternaries (v_cndmask, no scratch).
// ---------------------------------------------------------------------------
__global__ __launch_bounds__(256) void pdin_apply(const float* __restrict__ x,
                                                  const float* __restrict__ params,
                                                  float* __restrict__ out) {
    const int rblk = blockIdx.x;       // 0..31 -> 16 rows each
    const int c    = blockIdx.y;
    const int half = blockIdx.z;       // 0 = real, 1 = pre
    const float* P = params + c * PSTRIDE;
    const size_t cslab = (size_t)c * HW;

    if (half == 1) {
        const float scale = P[20], shift = P[21];
        const float4* src = reinterpret_cast<const float4*>(x + (size_t)CHW + cslab);
        float4*       dst = reinterpret_cast<float4*>(out + (size_t)CHW + cslab);
        const int base = rblk * 2048 + threadIdx.x;
#pragma unroll
        for (int i = 0; i < 8; ++i) {
            const int p = base + i * 256;
            float4 v = src[p];
            v.x = v.x * scale + shift;
            v.y = v.y * scale + shift;
            v.z = v.z * scale + shift;
            v.w = v.w * scale + shift;
            dst[p] = v;
        }
        return;
    }

    // real half: load 3x3 grids into named registers (static indexing only)
    const float g00 = P[0], g01 = P[1], g02 = P[2];
    const float g10 = P[3], g11 = P[4], g12 = P[5];
    const float g20 = P[6], g21 = P[7], g22 = P[8];
    const float s00 = P[9],  s01 = P[10], s02 = P[11];
    const float s10 = P[12], s11 = P[13], s12 = P[14];
    const float s20 = P[15], s21 = P[16], s22 = P[17];
    const float w = P[18], b = P[19];

    const float4* src = reinterpret_cast<const float4*>(x + cslab);
    float4*       dst = reinterpret_cast<float4*>(out + cslab);
    const int base = rblk * 2048 + threadIdx.x;
    constexpr float inv = 1.0f / 512.0f;

#pragma unroll
    for (int i = 0; i < 8; ++i) {
        const int p  = base + i * 256;          // float4 index within channel
        const int y  = p >> 7;                  // 128 float4 per row
        const int xq = p & 127;
        const int iy = (y  >= 256) ? 1 : 0;
        const int ix = (xq >= 64)  ? 1 : 0;     // xbase = xq*4 >= 256
        const float wy  = ((float)y + 0.5f) * inv + 0.5f - (float)iy;
        const float wx0 = ((float)(xq * 4) + 0.5f) * inv + 0.5f - (float)ix;

        // row-select by iy, then column-select by ix (reference interp order:
        // y first, then x)
        const float a0 = iy ? g10 : g00, a1 = iy ? g11 : g01, a2 = iy ? g12 : g02;
        const float b0 = iy ? g20 : g10, b1 = iy ? g21 : g11, b2 = iy ? g22 : g12;
        const float mtL = ix ? a1 : a0, mtR = ix ? a2 : a1;
        const float mbL = ix ? b1 : b0, mbR = ix ? b2 : b1;
        const float u0 = iy ? s10 : s00, u1 = iy ? s11 : s01, u2 = iy ? s12 : s02;
        const float v0 = iy ? s20 : s10, v1 = iy ? s21 : s11, v2 = iy ? s22 : s12;
        const float stL = ix ? u1 : u0, stR = ix ? u2 : u1;
        const float sbL = ix ? v1 : v0, sbR = ix ? v2 : v1;

        const float omwy = 1.0f - wy;
        const float mrowL = mtL * omwy + mbL * wy;
        const float mrowR = mtR * omwy + mbR * wy;
        const float srowL = stL * omwy + sbL * wy;
        const float srowR = stR * omwy + sbR * wy;

        float4 v = src[p];
        float r[4];
        const float in[4] = { v.x, v.y, v.z, v.w };
#pragma unroll
        for (int j = 0; j < 4; ++j) {
            const float wx   = wx0 + (float)j * inv;
            const float omwx = 1.0f - wx;
            const float m_v  = mrowL * omwx + mrowR * wx;
            const float s_v  = srowL * omwx + srowR * wx;
            r[j] = (in[j] - m_v) * s_v * w + b;
        }
        dst[p] = make_float4(r[0], r[1], r[2], r[3]);
    }
}

extern "C" void kernel_launch(void* const* d_in, const int* in_sizes, int n_in,
                              void* d_out, int out_size, void* d_ws, size_t ws_size,
                              hipStream_t stream) {
    const float* x   = (const float*)d_in[0];
    const float* mt  = (const float*)d_in[1];   // (C,12,12)
    const float* st  = (const float*)d_in[2];   // (C,12,12)
    const float* wgt = (const float*)d_in[3];   // (1,C,1,1)
    const float* bia = (const float*)d_in[4];   // (1,C,1,1)
    const int* ya  = (const int*)d_in[5];
    const int* xa  = (const int*)d_in[6];
    const int* pya = (const int*)d_in[7];
    const int* pxa = (const int*)d_in[8];
    float* out = (float*)d_out;

    float* partials = (float*)d_ws;             // C*NCHUNK*2 = 4096 floats
    float* params   = partials + Cc * NCHUNK * 2; // C*24 = 3072 floats

    pdin_reduce<<<dim3(NCHUNK, Cc), 256, 0, stream>>>(x, partials);
    pdin_finalize<<<1, 128, 0, stream>>>(partials, mt, st, wgt, bia,
                                         ya, xa, pya, pxa, params);
    pdin_apply<<<dim3(Hh / 16, Cc, 2), 256, 0, stream>>>(x, params, out);
}

// Round 5
// 114.528 us; speedup vs baseline: 1.1139x; 1.1139x over previous
//
#include <hip/hip_runtime.h>

// Problem constants (match reference)
constexpr int Cc  = 128;
constexpr int Hh  = 512;
constexpr int Ww  = 512;
constexpr int HW  = Hh * Ww;          // 262144
constexpr int CHW = Cc * HW;          // 33554432
constexpr int NCHUNK = 16;            // reduction blocks per channel
constexpr int PSTRIDE = 24;           // floats per channel in params

typedef float f32x4 __attribute__((ext_vector_type(4)));

// ---------------------------------------------------------------------------
// Kernel 1: per-channel partial sum / sumsq over pre_x (x[1], second half).
// grid = (NCHUNK, C), block = 256. Regular (cached) loads: this pass is what
// parks pre_x in the 256 MB Infinity Cache for the apply pass to reuse.
// Deterministic tree reduction (no float atomics -> replay-stable).
// ---------------------------------------------------------------------------
__global__ __launch_bounds__(256) void pdin_reduce(const float* __restrict__ x,
                                                   float* __restrict__ partials) {
    const int c = blockIdx.y, chunk = blockIdx.x, tid = threadIdx.x;
    const f32x4* src = reinterpret_cast<const f32x4*>(
        x + (size_t)CHW + (size_t)c * HW + (size_t)chunk * 16384);
    float s = 0.f, q = 0.f;
#pragma unroll
    for (int i = 0; i < 16; ++i) {
        f32x4 v = src[tid + i * 256];
        s += (v.x + v.y) + (v.z + v.w);
        q += (v.x * v.x + v.y * v.y) + (v.z * v.z + v.w * v.w);
    }
#pragma unroll
    for (int off = 32; off; off >>= 1) {
        s += __shfl_down(s, off);
        q += __shfl_down(q, off);
    }
    __shared__ float ls[4], lq[4];
    const int wave = tid >> 6, lane = tid & 63;
    if (lane == 0) { ls[wave] = s; lq[wave] = q; }
    __syncthreads();
    if (tid == 0) {
        float S = (ls[0] + ls[1]) + (ls[2] + ls[3]);
        float Q = (lq[0] + lq[1]) + (lq[2] + lq[3]);
        partials[(c * NCHUNK + chunk) * 2 + 0] = S;
        partials[(c * NCHUNK + chunk) * 2 + 1] = Q;
    }
}

// ---------------------------------------------------------------------------
// Kernel 2: finalize stats + build per-channel params (1 block, 128 threads).
// params[c*24]: [0..8] m grid, [9..17] 1/s grid, [18] w, [19] b,
//               [20] scale_pre = w/std, [21] shift_pre = b - mean*scale_pre
// ---------------------------------------------------------------------------
__global__ void pdin_finalize(const float* __restrict__ partials,
                              const float* __restrict__ mt,
                              const float* __restrict__ st,
                              const float* __restrict__ wgt,
                              const float* __restrict__ bia,
                              const int* __restrict__ ya_p, const int* __restrict__ xa_p,
                              const int* __restrict__ pya_p, const int* __restrict__ pxa_p,
                              float* __restrict__ params) {
    const int c = threadIdx.x;
    if (c >= Cc) return;
    float S = 0.f, Q = 0.f;
    for (int k = 0; k < NCHUNK; ++k) {
        S += partials[(c * NCHUNK + k) * 2 + 0];
        Q += partials[(c * NCHUNK + k) * 2 + 1];
    }
    const float Nf = (float)HW;
    const float mean = S / Nf;
    float var = (Q - S * mean) / (Nf - 1.0f);   // ddof=1
    var = fmaxf(var, 0.0f);
    const float stdv = sqrtf(var);

    const int ya = ya_p[0], xa = xa_p[0];
    const int wr = pya_p[0] + 1, wc = pxa_p[0] + 1;   // written table position
    const float* mtc = mt + c * 144;                   // 12x12 tables
    const float* stc = st + c * 144;

    // center of the 3x3 slice, post table-write, pre zero-substitution
    const bool cw = (ya + 1 == wr) && (xa + 1 == wc);
    const float cm = cw ? mean : mtc[(ya + 1) * 12 + (xa + 1)];
    const float cs = cw ? stdv : stc[(ya + 1) * 12 + (xa + 1)];

    float* P = params + c * PSTRIDE;
    for (int r = 0; r < 3; ++r)
        for (int k = 0; k < 3; ++k) {
            const int R = ya + r, L = xa + k;
            const bool hit = (R == wr) && (L == wc);
            float mv = hit ? mean : mtc[R * 12 + L];
            if (mv == 0.0f) mv = cm;
            float sv = hit ? stdv : stc[R * 12 + L];
            if (sv == 0.0f) sv = cs;
            P[r * 3 + k]     = mv;
            P[9 + r * 3 + k] = 1.0f / sv;
        }
    const float w = wgt[c], b = bia[c];
    P[18] = w;
    P[19] = b;
    const float sc = w / stdv;
    P[20] = sc;
    P[21] = b - mean * sc;
}

// ---------------------------------------------------------------------------
// Kernel 3: streaming elementwise pass over both halves.
// grid = (32 rowblocks, C, 2 halves), block = 256, 8 float4 per thread.
// blockIdx.z == 0 is the PRE half so it dispatches FIRST, while pre_x is
// still resident in the Infinity Cache from pdin_reduce (L3 hit, no HBM).
// real_x loads and ALL output stores are nontemporal (read-once/write-once)
// so they don't evict pre_x from L3.
// Real half: per-pixel bilinear from the 3x3 grid. A float4 quad always sits
// entirely on one side of the x=256 breakpoint (multiple of 4), so iy/ix are
// quad-uniform; selection is branch-free ternaries (v_cndmask, no scratch).
// ---------------------------------------------------------------------------
__global__ __launch_bounds__(256) void pdin_apply(const float* __restrict__ x,
                                                  const float* __restrict__ params,
                                                  float* __restrict__ out) {
    const int rblk = blockIdx.x;       // 0..31 -> 16 rows each
    const int c    = blockIdx.y;
    const int half = blockIdx.z;       // 0 = pre (first!), 1 = real
    const float* P = params + c * PSTRIDE;
    const size_t cslab = (size_t)c * HW;

    if (half == 0) {
        // ---- pre half: cached loads (L3 hit from reduce), nt stores ----
        const float scale = P[20], shift = P[21];
        const f32x4* src = reinterpret_cast<const f32x4*>(x + (size_t)CHW + cslab);
        f32x4*       dst = reinterpret_cast<f32x4*>(out + (size_t)CHW + cslab);
        const int base = rblk * 2048 + threadIdx.x;
#pragma unroll
        for (int i = 0; i < 8; ++i) {
            const int p = base + i * 256;
            f32x4 v = src[p];
            v.x = v.x * scale + shift;
            v.y = v.y * scale + shift;
            v.z = v.z * scale + shift;
            v.w = v.w * scale + shift;
            __builtin_nontemporal_store(v, dst + p);
        }
        return;
    }

    // ---- real half: nt loads (read-once), nt stores ----
    const float g00 = P[0], g01 = P[1], g02 = P[2];
    const float g10 = P[3], g11 = P[4], g12 = P[5];
    const float g20 = P[6], g21 = P[7], g22 = P[8];
    const float s00 = P[9],  s01 = P[10], s02 = P[11];
    const float s10 = P[12], s11 = P[13], s12 = P[14];
    const float s20 = P[15], s21 = P[16], s22 = P[17];
    const float w = P[18], b = P[19];

    const f32x4* src = reinterpret_cast<const f32x4*>(x + cslab);
    f32x4*       dst = reinterpret_cast<f32x4*>(out + cslab);
    const int base = rblk * 2048 + threadIdx.x;
    constexpr float inv = 1.0f / 512.0f;

#pragma unroll
    for (int i = 0; i < 8; ++i) {
        const int p  = base + i * 256;          // float4 index within channel
        const int y  = p >> 7;                  // 128 float4 per row
        const int xq = p & 127;
        const int iy = (y  >= 256) ? 1 : 0;
        const int ix = (xq >= 64)  ? 1 : 0;     // xbase = xq*4 >= 256
        const float wy  = ((float)y + 0.5f) * inv + 0.5f - (float)iy;
        const float wx0 = ((float)(xq * 4) + 0.5f) * inv + 0.5f - (float)ix;

        // row-select by iy, then column-select by ix (reference interp order:
        // y first, then x)
        const float a0 = iy ? g10 : g00, a1 = iy ? g11 : g01, a2 = iy ? g12 : g02;
        const float b0 = iy ? g20 : g10, b1 = iy ? g21 : g11, b2 = iy ? g22 : g12;
        const float mtL = ix ? a1 : a0, mtR = ix ? a2 : a1;
        const float mbL = ix ? b1 : b0, mbR = ix ? b2 : b1;
        const float u0 = iy ? s10 : s00, u1 = iy ? s11 : s01, u2 = iy ? s12 : s02;
        const float v0 = iy ? s20 : s10, v1 = iy ? s21 : s11, v2 = iy ? s22 : s12;
        const float stL = ix ? u1 : u0, stR = ix ? u2 : u1;
        const float sbL = ix ? v1 : v0, sbR = ix ? v2 : v1;

        const float omwy = 1.0f - wy;
        const float mrowL = mtL * omwy + mbL * wy;
        const float mrowR = mtR * omwy + mbR * wy;
        const float srowL = stL * omwy + sbL * wy;
        const float srowR = stR * omwy + sbR * wy;

        f32x4 v = __builtin_nontemporal_load(src + p);
        float r[4];
        const float in[4] = { v.x, v.y, v.z, v.w };
#pragma unroll
        for (int j = 0; j < 4; ++j) {
            const float wx   = wx0 + (float)j * inv;
            const float omwx = 1.0f - wx;
            const float m_v  = mrowL * omwx + mrowR * wx;
            const float s_v  = srowL * omwx + srowR * wx;
            r[j] = (in[j] - m_v) * s_v * w + b;
        }
        f32x4 o; o.x = r[0]; o.y = r[1]; o.z = r[2]; o.w = r[3];
        __builtin_nontemporal_store(o, dst + p);
    }
}

extern "C" void kernel_launch(void* const* d_in, const int* in_sizes, int n_in,
                              void* d_out, int out_size, void* d_ws, size_t ws_size,
                              hipStream_t stream) {
    const float* x   = (const float*)d_in[0];
    const float* mt  = (const float*)d_in[1];   // (C,12,12)
    const float* st  = (const float*)d_in[2];   // (C,12,12)
    const float* wgt = (const float*)d_in[3];   // (1,C,1,1)
    const float* bia = (const float*)d_in[4];   // (1,C,1,1)
    const int* ya  = (const int*)d_in[5];
    const int* xa  = (const int*)d_in[6];
    const int* pya = (const int*)d_in[7];
    const int* pxa = (const int*)d_in[8];
    float* out = (float*)d_out;

    float* partials = (float*)d_ws;               // C*NCHUNK*2 = 4096 floats
    float* params   = partials + Cc * NCHUNK * 2; // C*24 = 3072 floats

    pdin_reduce<<<dim3(NCHUNK, Cc), 256, 0, stream>>>(x, partials);
    pdin_finalize<<<1, 128, 0, stream>>>(partials, mt, st, wgt, bia,
                                         ya, xa, pya, pxa, params);
    pdin_apply<<<dim3(Hh / 16, Cc, 2), 256, 0, stream>>>(x, params, out);
}

// Round 6
// 109.273 us; speedup vs baseline: 1.1674x; 1.0481x over previous
//
#include <hip/hip_runtime.h>

// Problem constants (match reference)
constexpr int Cc  = 128;
constexpr int Hh  = 512;
constexpr int Ww  = 512;
constexpr int HW  = Hh * Ww;          // 262144
constexpr int CHW = Cc * HW;          // 33554432
constexpr int NCHUNK = 16;            // reduction blocks per channel

typedef float f32x4 __attribute__((ext_vector_type(4)));

// ---------------------------------------------------------------------------
// Kernel 1: per-channel partial sum / sumsq over pre_x (x[1], second half).
// grid = (NCHUNK, C), block = 256. Regular (cached) loads: this pass parks
// pre_x in the 256 MB Infinity Cache for the apply pass to reuse.
// Deterministic tree reduction (no float atomics -> replay-stable).
// ---------------------------------------------------------------------------
__global__ __launch_bounds__(256) void pdin_reduce(const float* __restrict__ x,
                                                   float* __restrict__ partials) {
    const int c = blockIdx.y, chunk = blockIdx.x, tid = threadIdx.x;
    const f32x4* src = reinterpret_cast<const f32x4*>(
        x + (size_t)CHW + (size_t)c * HW + (size_t)chunk * 16384);
    float s = 0.f, q = 0.f;
#pragma unroll
    for (int i = 0; i < 16; ++i) {
        f32x4 v = src[tid + i * 256];
        s += (v.x + v.y) + (v.z + v.w);
        q += (v.x * v.x + v.y * v.y) + (v.z * v.z + v.w * v.w);
    }
#pragma unroll
    for (int off = 32; off; off >>= 1) {
        s += __shfl_down(s, off);
        q += __shfl_down(q, off);
    }
    __shared__ float ls[4], lq[4];
    const int wave = tid >> 6, lane = tid & 63;
    if (lane == 0) { ls[wave] = s; lq[wave] = q; }
    __syncthreads();
    if (tid == 0) {
        float S = (ls[0] + ls[1]) + (ls[2] + ls[3]);
        float Q = (lq[0] + lq[1]) + (lq[2] + lq[3]);
        partials[(c * NCHUNK + chunk) * 2 + 0] = S;
        partials[(c * NCHUNK + chunk) * 2 + 1] = Q;
    }
}

// ---------------------------------------------------------------------------
// Kernel 2: streaming elementwise pass over both halves. The per-channel
// stats/grids are recomputed PER BLOCK from the 16 partials (uniform scalar
// work, ~50 ops, deterministic and identical across a channel's blocks) —
// this removes the device-serializing 1-block finalize kernel and one graph
// node gap.
// grid = (32 rowblocks, C, 2 halves), block = 256, 8 float4 per thread.
// blockIdx.z == 0 is the PRE half so it dispatches FIRST, while pre_x is
// still L3-resident from pdin_reduce. real_x loads and ALL output stores are
// nontemporal (read-once/write-once) to not evict pre_x.
// All 8 f32x4 loads are issued BEFORE compute/stores (batched -> 8 loads in
// flight per thread, no store-wait serialization).
// ---------------------------------------------------------------------------
__global__ __launch_bounds__(256) void pdin_apply(const float* __restrict__ x,
                                                  const float* __restrict__ partials,
                                                  const float* __restrict__ mt,
                                                  const float* __restrict__ st,
                                                  const float* __restrict__ wgt,
                                                  const float* __restrict__ bia,
                                                  const int* __restrict__ ya_p,
                                                  const int* __restrict__ xa_p,
                                                  const int* __restrict__ pya_p,
                                                  const int* __restrict__ pxa_p,
                                                  float* __restrict__ out) {
    const int rblk = blockIdx.x;       // 0..31 -> 16 rows each
    const int c    = blockIdx.y;
    const int half = blockIdx.z;       // 0 = pre (dispatches first), 1 = real

    // ---- per-block channel stats (uniform scalar path) ----
    float S = 0.f, Q = 0.f;
#pragma unroll
    for (int k = 0; k < NCHUNK; ++k) {
        S += partials[(c * NCHUNK + k) * 2 + 0];
        Q += partials[(c * NCHUNK + k) * 2 + 1];
    }
    const float Nf = (float)HW;
    const float mean = S / Nf;
    float var = (Q - S * mean) / (Nf - 1.0f);   // ddof=1
    var = fmaxf(var, 0.0f);
    const float stdv = sqrtf(var);
    const float w = wgt[c], b = bia[c];

    const size_t cslab = (size_t)c * HW;
    const int base = rblk * 2048 + threadIdx.x;

    if (half == 0) {
        // ---- pre half: cached loads (L3 hit from reduce), nt stores ----
        const float scale = w / stdv;
        const float shift = b - mean * scale;
        const f32x4* src = reinterpret_cast<const f32x4*>(x + (size_t)CHW + cslab);
        f32x4*       dst = reinterpret_cast<f32x4*>(out + (size_t)CHW + cslab);
        f32x4 v[8];
#pragma unroll
        for (int i = 0; i < 8; ++i) v[i] = src[base + i * 256];
#pragma unroll
        for (int i = 0; i < 8; ++i) {
            f32x4 o;
            o.x = v[i].x * scale + shift;
            o.y = v[i].y * scale + shift;
            o.z = v[i].z * scale + shift;
            o.w = v[i].w * scale + shift;
            __builtin_nontemporal_store(o, dst + base + i * 256);
        }
        return;
    }

    // ---- real half: build 3x3 grids (uniform), nt loads + nt stores ----
    const int ya = ya_p[0], xa = xa_p[0];
    const int wr = pya_p[0] + 1, wc = pxa_p[0] + 1;   // written table position
    const float* mtc = mt + c * 144;                   // 12x12 tables
    const float* stc = st + c * 144;

    // center of the 3x3 slice, post table-write, pre zero-substitution
    const bool cw = (ya + 1 == wr) && (xa + 1 == wc);
    const float cm = cw ? mean : mtc[(ya + 1) * 12 + (xa + 1)];
    const float cs = cw ? stdv : stc[(ya + 1) * 12 + (xa + 1)];

    float G[9], R9[9];                 // mean grid, 1/std grid (const indices only)
#pragma unroll
    for (int r = 0; r < 3; ++r)
#pragma unroll
        for (int k = 0; k < 3; ++k) {
            const int Rr = ya + r, L = xa + k;
            const bool hit = (Rr == wr) && (L == wc);
            float mv = hit ? mean : mtc[Rr * 12 + L];
            if (mv == 0.0f) mv = cm;
            float sv = hit ? stdv : stc[Rr * 12 + L];
            if (sv == 0.0f) sv = cs;
            G[r * 3 + k]  = mv;
            R9[r * 3 + k] = 1.0f / sv;
        }

    const f32x4* src = reinterpret_cast<const f32x4*>(x + cslab);
    f32x4*       dst = reinterpret_cast<f32x4*>(out + cslab);
    constexpr float inv = 1.0f / 512.0f;

    f32x4 v[8];
#pragma unroll
    for (int i = 0; i < 8; ++i)
        v[i] = __builtin_nontemporal_load(src + base + i * 256);

#pragma unroll
    for (int i = 0; i < 8; ++i) {
        const int p  = base + i * 256;          // float4 index within channel
        const int y  = p >> 7;                  // 128 float4 per row
        const int xq = p & 127;
        const int iy = (y  >= 256) ? 1 : 0;
        const int ix = (xq >= 64)  ? 1 : 0;     // xbase = xq*4 >= 256
        const float wy  = ((float)y + 0.5f) * inv + 0.5f - (float)iy;
        const float wx0 = ((float)(xq * 4) + 0.5f) * inv + 0.5f - (float)ix;

        // row-select by iy, then column-select by ix (reference interp order:
        // y first, then x). All grid indices are compile-time constants.
        const float a0 = iy ? G[3] : G[0], a1 = iy ? G[4] : G[1], a2 = iy ? G[5] : G[2];
        const float b0 = iy ? G[6] : G[3], b1 = iy ? G[7] : G[4], b2 = iy ? G[8] : G[5];
        const float mtL = ix ? a1 : a0, mtR = ix ? a2 : a1;
        const float mbL = ix ? b1 : b0, mbR = ix ? b2 : b1;
        const float u0 = iy ? R9[3] : R9[0], u1 = iy ? R9[4] : R9[1], u2 = iy ? R9[5] : R9[2];
        const float v0 = iy ? R9[6] : R9[3], v1 = iy ? R9[7] : R9[4], v2 = iy ? R9[8] : R9[5];
        const float stL = ix ? u1 : u0, stR = ix ? u2 : u1;
        const float sbL = ix ? v1 : v0, sbR = ix ? v2 : v1;

        const float omwy = 1.0f - wy;
        const float mrowL = mtL * omwy + mbL * wy;
        const float mrowR = mtR * omwy + mbR * wy;
        const float srowL = stL * omwy + sbL * wy;
        const float srowR = stR * omwy + sbR * wy;

        float r[4];
        const float in4[4] = { v[i].x, v[i].y, v[i].z, v[i].w };
#pragma unroll
        for (int j = 0; j < 4; ++j) {
            const float wx   = wx0 + (float)j * inv;
            const float omwx = 1.0f - wx;
            const float m_v  = mrowL * omwx + mrowR * wx;
            const float s_v  = srowL * omwx + srowR * wx;
            r[j] = (in4[j] - m_v) * s_v * w + b;
        }
        f32x4 o; o.x = r[0]; o.y = r[1]; o.z = r[2]; o.w = r[3];
        __builtin_nontemporal_store(o, dst + p);
    }
}

extern "C" void kernel_launch(void* const* d_in, const int* in_sizes, int n_in,
                              void* d_out, int out_size, void* d_ws, size_t ws_size,
                              hipStream_t stream) {
    const float* x   = (const float*)d_in[0];
    const float* mt  = (const float*)d_in[1];   // (C,12,12)
    const float* st  = (const float*)d_in[2];   // (C,12,12)
    const float* wgt = (const float*)d_in[3];   // (1,C,1,1)
    const float* bia = (const float*)d_in[4];   // (1,C,1,1)
    const int* ya  = (const int*)d_in[5];
    const int* xa  = (const int*)d_in[6];
    const int* pya = (const int*)d_in[7];
    const int* pxa = (const int*)d_in[8];
    float* out = (float*)d_out;

    float* partials = (float*)d_ws;             // C*NCHUNK*2 = 4096 floats

    pdin_reduce<<<dim3(NCHUNK, Cc), 256, 0, stream>>>(x, partials);
    pdin_apply<<<dim3(Hh / 16, Cc, 2), 256, 0, stream>>>(
        x, partials, mt, st, wgt, bia, ya, xa, pya, pxa, out);
}